// Round 1
// baseline (2774.125 us; speedup 1.0000x reference)
//
#include <hip/hip_runtime.h>

#define NN 100000
#define NE 800000

// ---------------- degree / normalization ----------------
__global__ void k_deg(const int* __restrict__ dst, float* __restrict__ deg) {
    int e = blockIdx.x * 256 + threadIdx.x;
    if (e < NE) unsafeAtomicAdd(&deg[dst[e]], 1.0f);
}

__global__ void k_dis(const float* __restrict__ deg, float* __restrict__ dis) {
    int i = blockIdx.x * 256 + threadIdx.x;
    if (i < NN) dis[i] = rsqrtf(deg[i] + 1.0f);
}

__global__ void k_norm(const int* __restrict__ src, const int* __restrict__ dst,
                       const float* __restrict__ dis, float* __restrict__ nrm) {
    int e = blockIdx.x * 256 + threadIdx.x;
    if (e < NE) nrm[e] = dis[src[e]] * dis[dst[e]];
}

// ---------------- GEMM 1: H1 = X @ W1 ; AGG1 = H1 * dis^2 ----------------
// M=100000, K=100, N=100 (padded 128). 128-row tile, 8x8 microtile, 256 thr.
__global__ __launch_bounds__(256) void k_gemm1(
    const float* __restrict__ X, const float* __restrict__ W,
    const float* __restrict__ dis,
    float* __restrict__ H, float* __restrict__ AGG)
{
    __shared__ float Ws[100 * 128];
    __shared__ float Xs[20 * 128];
    const int tid = threadIdx.x;
    const int tcol = tid & 15;
    const int trow = tid >> 4;
    const int row0 = blockIdx.x * 128;

    for (int idx = tid; idx < 100 * 128; idx += 256) {
        int k = idx >> 7, c = idx & 127;
        Ws[idx] = (c < 100) ? W[k * 100 + c] : 0.0f;
    }

    float acc[8][8];
    #pragma unroll
    for (int r = 0; r < 8; ++r)
        #pragma unroll
        for (int c = 0; c < 8; ++c) acc[r][c] = 0.0f;

    for (int kb = 0; kb < 5; ++kb) {
        __syncthreads();
        {
            int rl = tid >> 1, half = tid & 1;
            int grow = row0 + rl;
            const float* ap = X + (size_t)grow * 100 + kb * 20 + half * 10;
            bool v = grow < NN;
            float tmp[10];
            #pragma unroll
            for (int q = 0; q < 10; ++q) tmp[q] = v ? ap[q] : 0.0f;
            #pragma unroll
            for (int q = 0; q < 10; ++q) Xs[(half * 10 + q) * 128 + rl] = tmp[q];
        }
        __syncthreads();
        #pragma unroll 4
        for (int kk = 0; kk < 20; ++kk) {
            int k = kb * 20 + kk;
            float4 a0 = *(const float4*)&Xs[kk * 128 + trow * 8];
            float4 a1 = *(const float4*)&Xs[kk * 128 + trow * 8 + 4];
            float4 w0 = *(const float4*)&Ws[k * 128 + tcol * 8];
            float4 w1 = *(const float4*)&Ws[k * 128 + tcol * 8 + 4];
            float av[8] = {a0.x, a0.y, a0.z, a0.w, a1.x, a1.y, a1.z, a1.w};
            float wv[8] = {w0.x, w0.y, w0.z, w0.w, w1.x, w1.y, w1.z, w1.w};
            #pragma unroll
            for (int r = 0; r < 8; ++r)
                #pragma unroll
                for (int c = 0; c < 8; ++c)
                    acc[r][c] += av[r] * wv[c];
        }
    }

    #pragma unroll
    for (int r = 0; r < 8; ++r) {
        int gr = row0 + trow * 8 + r;
        if (gr >= NN) continue;
        float d = dis[gr];
        float d2 = d * d;
        #pragma unroll
        for (int cc = 0; cc < 8; cc += 4) {
            int c = tcol * 8 + cc;
            if (c < 100) {
                float4 v = make_float4(acc[r][cc], acc[r][cc + 1], acc[r][cc + 2], acc[r][cc + 3]);
                *(float4*)&H[(size_t)gr * 100 + c] = v;
                float4 s = make_float4(v.x * d2, v.y * d2, v.z * d2, v.w * d2);
                *(float4*)&AGG[(size_t)gr * 100 + c] = s;
            }
        }
    }
}

// ---------------- edge scatter: AGG[dst] += H[src] * norm ----------------
// one thread per (edge, float4 channel group); 25 groups of 4 channels.
__global__ void k_scatter(const int* __restrict__ src, const int* __restrict__ dst,
                          const float* __restrict__ nrm,
                          const float* __restrict__ H, float* __restrict__ AGG)
{
    int i = blockIdx.x * 256 + threadIdx.x;
    if (i < NE * 25) {
        int e = i / 25;
        int j = i - e * 25;
        int s = src[e];
        int d = dst[e];
        float w = nrm[e];
        float4 v = *(const float4*)(H + (size_t)s * 100 + j * 4);
        float* p = AGG + (size_t)d * 100 + j * 4;
        unsafeAtomicAdd(p + 0, v.x * w);
        unsafeAtomicAdd(p + 1, v.y * w);
        unsafeAtomicAdd(p + 2, v.z * w);
        unsafeAtomicAdd(p + 3, v.w * w);
    }
}

// ---------------- h = relu(AGG1 + b1) ; AGG2 = h * dis^2 ----------------
__global__ void k_relu_init(const float* __restrict__ AGG1, const float* __restrict__ b1,
                            const float* __restrict__ dis,
                            float* __restrict__ h, float* __restrict__ AGG2)
{
    int i = blockIdx.x * 256 + threadIdx.x;
    if (i < NN * 25) {
        int row = i / 25;
        int j = i - row * 25;
        float4 v = *(const float4*)(AGG1 + (size_t)i * 4);
        float4 b = *(const float4*)(b1 + j * 4);
        float4 hv;
        hv.x = fmaxf(v.x + b.x, 0.0f);
        hv.y = fmaxf(v.y + b.y, 0.0f);
        hv.z = fmaxf(v.z + b.z, 0.0f);
        hv.w = fmaxf(v.w + b.w, 0.0f);
        *(float4*)(h + (size_t)i * 4) = hv;
        float d = dis[row];
        float d2 = d * d;
        float4 s = make_float4(hv.x * d2, hv.y * d2, hv.z * d2, hv.w * d2);
        *(float4*)(AGG2 + (size_t)i * 4) = s;
    }
}

// ---------------- GEMM 2: out = AGG2 @ [Wmu|Wls] + [bmu|bls] ----------------
__global__ __launch_bounds__(256) void k_gemm2(
    const float* __restrict__ A,
    const float* __restrict__ Wmu, const float* __restrict__ Wls,
    const float* __restrict__ bmu, const float* __restrict__ bls,
    float* __restrict__ outmu, float* __restrict__ outls)
{
    __shared__ float Ws[100 * 128];
    __shared__ float Xs[20 * 128];
    const int tid = threadIdx.x;
    const int tcol = tid & 15;
    const int trow = tid >> 4;
    const int row0 = blockIdx.x * 128;

    for (int idx = tid; idx < 100 * 128; idx += 256) {
        int k = idx >> 7, c = idx & 127;
        float w = 0.0f;
        if (c < 50) w = Wmu[k * 50 + c];
        else if (c < 100) w = Wls[k * 50 + (c - 50)];
        Ws[idx] = w;
    }

    float acc[8][8];
    #pragma unroll
    for (int r = 0; r < 8; ++r)
        #pragma unroll
        for (int c = 0; c < 8; ++c) acc[r][c] = 0.0f;

    for (int kb = 0; kb < 5; ++kb) {
        __syncthreads();
        {
            int rl = tid >> 1, half = tid & 1;
            int grow = row0 + rl;
            const float* ap = A + (size_t)grow * 100 + kb * 20 + half * 10;
            bool v = grow < NN;
            float tmp[10];
            #pragma unroll
            for (int q = 0; q < 10; ++q) tmp[q] = v ? ap[q] : 0.0f;
            #pragma unroll
            for (int q = 0; q < 10; ++q) Xs[(half * 10 + q) * 128 + rl] = tmp[q];
        }
        __syncthreads();
        #pragma unroll 4
        for (int kk = 0; kk < 20; ++kk) {
            int k = kb * 20 + kk;
            float4 a0 = *(const float4*)&Xs[kk * 128 + trow * 8];
            float4 a1 = *(const float4*)&Xs[kk * 128 + trow * 8 + 4];
            float4 w0 = *(const float4*)&Ws[k * 128 + tcol * 8];
            float4 w1 = *(const float4*)&Ws[k * 128 + tcol * 8 + 4];
            float av[8] = {a0.x, a0.y, a0.z, a0.w, a1.x, a1.y, a1.z, a1.w};
            float wv[8] = {w0.x, w0.y, w0.z, w0.w, w1.x, w1.y, w1.z, w1.w};
            #pragma unroll
            for (int r = 0; r < 8; ++r)
                #pragma unroll
                for (int c = 0; c < 8; ++c)
                    acc[r][c] += av[r] * wv[c];
        }
    }

    #pragma unroll
    for (int r = 0; r < 8; ++r) {
        int gr = row0 + trow * 8 + r;
        if (gr >= NN) continue;
        #pragma unroll
        for (int cc = 0; cc < 8; ++cc) {
            int c = tcol * 8 + cc;
            if (c < 50) {
                outmu[(size_t)gr * 50 + c] = acc[r][cc] + bmu[c];
            } else if (c < 100) {
                outls[(size_t)gr * 50 + (c - 50)] = acc[r][cc] + bls[c - 50];
            }
        }
    }
}

extern "C" void kernel_launch(void* const* d_in, const int* in_sizes, int n_in,
                              void* d_out, int out_size, void* d_ws, size_t ws_size,
                              hipStream_t stream)
{
    const float* x   = (const float*)d_in[0];
    const int*   ei  = (const int*)d_in[1];
    const float* W1  = (const float*)d_in[2];
    const float* b1  = (const float*)d_in[3];
    const float* Wmu = (const float*)d_in[4];
    const float* bmu = (const float*)d_in[5];
    const float* Wls = (const float*)d_in[6];
    const float* bls = (const float*)d_in[7];
    float* out = (float*)d_out;

    const int* src = ei;
    const int* dst = ei + NE;

    // workspace layout (floats): deg[100k] dis[100k] nrm[800k] H1[10M] AGG1[10M] AGG2[10M]
    float* ws   = (float*)d_ws;
    float* deg  = ws;
    float* dis  = ws + 100000;
    float* nrm  = ws + 200000;
    float* H1   = ws + 1000000;   // reused as h after relu
    float* AGG1 = ws + 11000000;
    float* AGG2 = ws + 21000000;

    hipMemsetAsync(deg, 0, NN * sizeof(float), stream);
    k_deg<<<(NE + 255) / 256, 256, 0, stream>>>(dst, deg);
    k_dis<<<(NN + 255) / 256, 256, 0, stream>>>(deg, dis);
    k_norm<<<(NE + 255) / 256, 256, 0, stream>>>(src, dst, dis, nrm);

    k_gemm1<<<(NN + 127) / 128, 256, 0, stream>>>(x, W1, dis, H1, AGG1);
    k_scatter<<<(NE * 25 + 255) / 256, 256, 0, stream>>>(src, dst, nrm, H1, AGG1);
    k_relu_init<<<(NN * 25 + 255) / 256, 256, 0, stream>>>(AGG1, b1, dis, H1, AGG2);
    k_scatter<<<(NE * 25 + 255) / 256, 256, 0, stream>>>(src, dst, nrm, H1, AGG2);
    k_gemm2<<<(NN + 127) / 128, 256, 0, stream>>>(AGG2, Wmu, Wls, bmu, bls,
                                                  out, out + (size_t)NN * 50);
}

// Round 2
// 638.004 us; speedup vs baseline: 4.3481x; 4.3481x over previous
//
#include <hip/hip_runtime.h>

#define NN 100000
#define NE 800000
#define NBLK 196   // ceil(100000/512) scan blocks

// ---------------- degree (int) ----------------
__global__ void k_degi(const int* __restrict__ dst, int* __restrict__ deg) {
    int e = blockIdx.x * 256 + threadIdx.x;
    if (e < NE) atomicAdd(&deg[dst[e]], 1);
}

__global__ void k_dis(const int* __restrict__ deg, float* __restrict__ dis) {
    int i = blockIdx.x * 256 + threadIdx.x;
    if (i < NN) dis[i] = rsqrtf((float)deg[i] + 1.0f);
}

// ---------------- 3-pass exclusive scan of deg -> off ----------------
__global__ __launch_bounds__(256) void k_scan1(const int* __restrict__ deg, int* __restrict__ bsum) {
    __shared__ int s[256];
    int b = blockIdx.x, t = threadIdx.x;
    int g0 = b * 512;
    int v = 0;
    int g1 = g0 + t, g2 = g0 + t + 256;
    if (g1 < NN) v += deg[g1];
    if (g2 < NN) v += deg[g2];
    s[t] = v;
    __syncthreads();
    for (int o = 128; o > 0; o >>= 1) {
        if (t < o) s[t] += s[t + o];
        __syncthreads();
    }
    if (t == 0) bsum[b] = s[0];
}

__global__ __launch_bounds__(256) void k_scan2(const int* __restrict__ bsum, int* __restrict__ base) {
    __shared__ int s[NBLK];
    int t = threadIdx.x;
    if (t < NBLK) s[t] = bsum[t];
    __syncthreads();
    if (t == 0) {
        int run = 0;
        for (int i = 0; i < NBLK; ++i) { int v = s[i]; s[i] = run; run += v; }
    }
    __syncthreads();
    if (t < NBLK) base[t] = s[t];
}

__global__ __launch_bounds__(256) void k_scan3(const int* __restrict__ deg, const int* __restrict__ base,
                                               int* __restrict__ off) {
    __shared__ int s[2][512];
    int b = blockIdx.x, t = threadIdx.x;
    int g0 = b * 512;
    #pragma unroll
    for (int q = 0; q < 2; ++q) {
        int j = t + q * 256, g = g0 + j;
        s[0][j] = (g < NN) ? deg[g] : 0;
    }
    __syncthreads();
    int cur = 0;
    for (int o = 1; o < 512; o <<= 1) {
        int nxt = cur ^ 1;
        #pragma unroll
        for (int q = 0; q < 2; ++q) {
            int j = t + q * 256;
            s[nxt][j] = s[cur][j] + ((j >= o) ? s[cur][j - o] : 0);
        }
        cur = nxt;
        __syncthreads();
    }
    int bb = base[b];
    #pragma unroll
    for (int q = 0; q < 2; ++q) {
        int j = t + q * 256, g = g0 + j;
        if (g <= NN) off[g] = bb + ((j > 0) ? s[cur][j - 1] : 0);
    }
}

// ---------------- fill CSR slots ----------------
__global__ void k_fill(const int* __restrict__ src, const int* __restrict__ dst,
                       const int* __restrict__ off, int* __restrict__ cur,
                       const float* __restrict__ dis,
                       int* __restrict__ ssrc, float* __restrict__ snrm) {
    int e = blockIdx.x * 256 + threadIdx.x;
    if (e < NE) {
        int s = src[e], d = dst[e];
        int pos = off[d] + atomicAdd(&cur[d], 1);
        ssrc[pos] = s;
        snrm[pos] = dis[s] * dis[d];
    }
}

// ---------------- GEMM 1: H1 = X @ W1 ----------------
__global__ __launch_bounds__(256) void k_gemm1(
    const float* __restrict__ X, const float* __restrict__ W,
    float* __restrict__ H)
{
    __shared__ float Ws[100 * 128];
    __shared__ float Xs[20 * 128];
    const int tid = threadIdx.x;
    const int tcol = tid & 15;
    const int trow = tid >> 4;
    const int row0 = blockIdx.x * 128;

    for (int idx = tid; idx < 100 * 128; idx += 256) {
        int k = idx >> 7, c = idx & 127;
        Ws[idx] = (c < 100) ? W[k * 100 + c] : 0.0f;
    }

    float acc[8][8];
    #pragma unroll
    for (int r = 0; r < 8; ++r)
        #pragma unroll
        for (int c = 0; c < 8; ++c) acc[r][c] = 0.0f;

    for (int kb = 0; kb < 5; ++kb) {
        __syncthreads();
        {
            int rl = tid >> 1, half = tid & 1;
            int grow = row0 + rl;
            const float* ap = X + (size_t)grow * 100 + kb * 20 + half * 10;
            bool v = grow < NN;
            float tmp[10];
            #pragma unroll
            for (int q = 0; q < 10; ++q) tmp[q] = v ? ap[q] : 0.0f;
            #pragma unroll
            for (int q = 0; q < 10; ++q) Xs[(half * 10 + q) * 128 + rl] = tmp[q];
        }
        __syncthreads();
        #pragma unroll 4
        for (int kk = 0; kk < 20; ++kk) {
            int k = kb * 20 + kk;
            float4 a0 = *(const float4*)&Xs[kk * 128 + trow * 8];
            float4 a1 = *(const float4*)&Xs[kk * 128 + trow * 8 + 4];
            float4 w0 = *(const float4*)&Ws[k * 128 + tcol * 8];
            float4 w1 = *(const float4*)&Ws[k * 128 + tcol * 8 + 4];
            float av[8] = {a0.x, a0.y, a0.z, a0.w, a1.x, a1.y, a1.z, a1.w};
            float wv[8] = {w0.x, w0.y, w0.z, w0.w, w1.x, w1.y, w1.z, w1.w};
            #pragma unroll
            for (int r = 0; r < 8; ++r)
                #pragma unroll
                for (int c = 0; c < 8; ++c)
                    acc[r][c] += av[r] * wv[c];
        }
    }

    #pragma unroll
    for (int r = 0; r < 8; ++r) {
        int gr = row0 + trow * 8 + r;
        if (gr >= NN) continue;
        #pragma unroll
        for (int cc = 0; cc < 8; cc += 4) {
            int c = tcol * 8 + cc;
            if (c < 100) {
                float4 v = make_float4(acc[r][cc], acc[r][cc + 1], acc[r][cc + 2], acc[r][cc + 3]);
                *(float4*)&H[(size_t)gr * 100 + c] = v;
            }
        }
    }
}

// ---------------- aggregation (gather, no atomics) ----------------
// PHASE 1: out = relu(self + edgesum + b1)   PHASE 2: out = self + edgesum
template<int PHASE>
__global__ __launch_bounds__(256) void k_agg(
    const float* __restrict__ Hin,
    const int* __restrict__ off, const int* __restrict__ ssrc, const float* __restrict__ snrm,
    const float* __restrict__ dis, const float* __restrict__ bias,
    float* __restrict__ out)
{
    int i = blockIdx.x * 256 + threadIdx.x;
    if (i >= NN * 100) return;
    int node = i / 100;
    int ch = i - node * 100;
    float d = dis[node];
    float acc = Hin[(size_t)node * 100 + ch] * d * d;
    int e0 = off[node], e1 = off[node + 1];
    for (int e = e0; e < e1; ++e) {
        int s = ssrc[e];
        float w = snrm[e];
        acc += Hin[(size_t)s * 100 + ch] * w;
    }
    if (PHASE == 1) acc = fmaxf(acc + bias[ch], 0.0f);
    out[i] = acc;
}

// ---------------- GEMM 2: out = AGG2 @ [Wmu|Wls] + [bmu|bls] ----------------
__global__ __launch_bounds__(256) void k_gemm2(
    const float* __restrict__ A,
    const float* __restrict__ Wmu, const float* __restrict__ Wls,
    const float* __restrict__ bmu, const float* __restrict__ bls,
    float* __restrict__ outmu, float* __restrict__ outls)
{
    __shared__ float Ws[100 * 128];
    __shared__ float Xs[20 * 128];
    const int tid = threadIdx.x;
    const int tcol = tid & 15;
    const int trow = tid >> 4;
    const int row0 = blockIdx.x * 128;

    for (int idx = tid; idx < 100 * 128; idx += 256) {
        int k = idx >> 7, c = idx & 127;
        float w = 0.0f;
        if (c < 50) w = Wmu[k * 50 + c];
        else if (c < 100) w = Wls[k * 50 + (c - 50)];
        Ws[idx] = w;
    }

    float acc[8][8];
    #pragma unroll
    for (int r = 0; r < 8; ++r)
        #pragma unroll
        for (int c = 0; c < 8; ++c) acc[r][c] = 0.0f;

    for (int kb = 0; kb < 5; ++kb) {
        __syncthreads();
        {
            int rl = tid >> 1, half = tid & 1;
            int grow = row0 + rl;
            const float* ap = A + (size_t)grow * 100 + kb * 20 + half * 10;
            bool v = grow < NN;
            float tmp[10];
            #pragma unroll
            for (int q = 0; q < 10; ++q) tmp[q] = v ? ap[q] : 0.0f;
            #pragma unroll
            for (int q = 0; q < 10; ++q) Xs[(half * 10 + q) * 128 + rl] = tmp[q];
        }
        __syncthreads();
        #pragma unroll 4
        for (int kk = 0; kk < 20; ++kk) {
            int k = kb * 20 + kk;
            float4 a0 = *(const float4*)&Xs[kk * 128 + trow * 8];
            float4 a1 = *(const float4*)&Xs[kk * 128 + trow * 8 + 4];
            float4 w0 = *(const float4*)&Ws[k * 128 + tcol * 8];
            float4 w1 = *(const float4*)&Ws[k * 128 + tcol * 8 + 4];
            float av[8] = {a0.x, a0.y, a0.z, a0.w, a1.x, a1.y, a1.z, a1.w};
            float wv[8] = {w0.x, w0.y, w0.z, w0.w, w1.x, w1.y, w1.z, w1.w};
            #pragma unroll
            for (int r = 0; r < 8; ++r)
                #pragma unroll
                for (int c = 0; c < 8; ++c)
                    acc[r][c] += av[r] * wv[c];
        }
    }

    #pragma unroll
    for (int r = 0; r < 8; ++r) {
        int gr = row0 + trow * 8 + r;
        if (gr >= NN) continue;
        #pragma unroll
        for (int cc = 0; cc < 8; ++cc) {
            int c = tcol * 8 + cc;
            if (c < 50) {
                outmu[(size_t)gr * 50 + c] = acc[r][cc] + bmu[c];
            } else if (c < 100) {
                outls[(size_t)gr * 50 + (c - 50)] = acc[r][cc] + bls[c - 50];
            }
        }
    }
}

extern "C" void kernel_launch(void* const* d_in, const int* in_sizes, int n_in,
                              void* d_out, int out_size, void* d_ws, size_t ws_size,
                              hipStream_t stream)
{
    const float* x   = (const float*)d_in[0];
    const int*   ei  = (const int*)d_in[1];
    const float* W1  = (const float*)d_in[2];
    const float* b1  = (const float*)d_in[3];
    const float* Wmu = (const float*)d_in[4];
    const float* bmu = (const float*)d_in[5];
    const float* Wls = (const float*)d_in[6];
    const float* bls = (const float*)d_in[7];
    float* out = (float*)d_out;

    const int* src = ei;
    const int* dst = ei + NE;

    // workspace layout (element offsets, 4B each)
    int*   wsI  = (int*)d_ws;
    float* wsF  = (float*)d_ws;
    int*   deg  = wsI;                 // [0, 100000)  also reused as cursor
    int*   off  = wsI + 100000;        // [100000, 200001)
    int*   bsum = wsI + 200064;        // 256
    int*   base = wsI + 200384;        // 256
    float* dis  = wsF + 200704;        // 100000
    int*   ssrc = wsI + 300704;        // 800000
    float* snrm = wsF + 1100704;       // 800000
    float* buf0 = wsF + 2000000;       // 10M : H1, later AGG2
    float* buf1 = wsF + 12000000;      // 10M : h

    hipMemsetAsync(deg, 0, NN * sizeof(int), stream);
    k_degi<<<(NE + 255) / 256, 256, 0, stream>>>(dst, deg);
    k_dis<<<(NN + 255) / 256, 256, 0, stream>>>(deg, dis);
    k_scan1<<<NBLK, 256, 0, stream>>>(deg, bsum);
    k_scan2<<<1, 256, 0, stream>>>(bsum, base);
    k_scan3<<<NBLK, 256, 0, stream>>>(deg, base, off);
    hipMemsetAsync(deg, 0, NN * sizeof(int), stream);   // reuse as cursor
    k_fill<<<(NE + 255) / 256, 256, 0, stream>>>(src, dst, off, deg, dis, ssrc, snrm);

    // layer 1: H1 = X@W1 ; h = relu(Agg(H1) + b1)
    k_gemm1<<<(NN + 127) / 128, 256, 0, stream>>>(x, W1, buf0);
    k_agg<1><<<(NN * 100 + 255) / 256, 256, 0, stream>>>(buf0, off, ssrc, snrm, dis, b1, buf1);
    // layer 2: AGG2 = Agg(h) ; out = AGG2@[Wmu|Wls] + bias
    k_agg<2><<<(NN * 100 + 255) / 256, 256, 0, stream>>>(buf1, off, ssrc, snrm, dis, b1, buf0);
    k_gemm2<<<(NN + 127) / 128, 256, 0, stream>>>(buf0, Wmu, Wls, bmu, bls,
                                                  out, out + (size_t)NN * 50);
}

// Round 3
// 439.319 us; speedup vs baseline: 6.3146x; 1.4523x over previous
//
#include <hip/hip_runtime.h>

#define NN 100000
#define NE 800000
#define NBLK 196   // ceil(100000/512) scan blocks

typedef unsigned short ushort_t;

__device__ __forceinline__ float bf2f(ushort_t u) {
    union { unsigned int i; float f; } v; v.i = ((unsigned int)u) << 16; return v.f;
}
__device__ __forceinline__ ushort_t f2bf(float f) {
    union { float f; unsigned int i; } v; v.f = f;
    unsigned int b = v.i + 0x7FFF + ((v.i >> 16) & 1);
    return (ushort_t)(b >> 16);
}

// ---------------- degree (int) ----------------
__global__ void k_degi(const int* __restrict__ dst, int* __restrict__ deg) {
    int e = blockIdx.x * 256 + threadIdx.x;
    if (e < NE) atomicAdd(&deg[dst[e]], 1);
}

__global__ void k_dis(const int* __restrict__ deg, float* __restrict__ dis) {
    int i = blockIdx.x * 256 + threadIdx.x;
    if (i < NN) dis[i] = rsqrtf((float)deg[i] + 1.0f);
}

// ---------------- 3-pass exclusive scan of deg -> off ----------------
__global__ __launch_bounds__(256) void k_scan1(const int* __restrict__ deg, int* __restrict__ bsum) {
    __shared__ int s[256];
    int b = blockIdx.x, t = threadIdx.x;
    int g0 = b * 512;
    int v = 0;
    int g1 = g0 + t, g2 = g0 + t + 256;
    if (g1 < NN) v += deg[g1];
    if (g2 < NN) v += deg[g2];
    s[t] = v;
    __syncthreads();
    for (int o = 128; o > 0; o >>= 1) {
        if (t < o) s[t] += s[t + o];
        __syncthreads();
    }
    if (t == 0) bsum[b] = s[0];
}

__global__ __launch_bounds__(256) void k_scan2(const int* __restrict__ bsum, int* __restrict__ base) {
    __shared__ int s[NBLK];
    int t = threadIdx.x;
    if (t < NBLK) s[t] = bsum[t];
    __syncthreads();
    if (t == 0) {
        int run = 0;
        for (int i = 0; i < NBLK; ++i) { int v = s[i]; s[i] = run; run += v; }
    }
    __syncthreads();
    if (t < NBLK) base[t] = s[t];
}

__global__ __launch_bounds__(256) void k_scan3(const int* __restrict__ deg, const int* __restrict__ base,
                                               int* __restrict__ off) {
    __shared__ int s[2][512];
    int b = blockIdx.x, t = threadIdx.x;
    int g0 = b * 512;
    #pragma unroll
    for (int q = 0; q < 2; ++q) {
        int j = t + q * 256, g = g0 + j;
        s[0][j] = (g < NN) ? deg[g] : 0;
    }
    __syncthreads();
    int cur = 0;
    for (int o = 1; o < 512; o <<= 1) {
        int nxt = cur ^ 1;
        #pragma unroll
        for (int q = 0; q < 2; ++q) {
            int j = t + q * 256;
            s[nxt][j] = s[cur][j] + ((j >= o) ? s[cur][j - o] : 0);
        }
        cur = nxt;
        __syncthreads();
    }
    int bb = base[b];
    #pragma unroll
    for (int q = 0; q < 2; ++q) {
        int j = t + q * 256, g = g0 + j;
        if (g <= NN) off[g] = bb + ((j > 0) ? s[cur][j - 1] : 0);
    }
}

// ---------------- fill CSR slots: eidx[pos] = {src, bitcast(norm)} ----------------
__global__ void k_fill(const int* __restrict__ src, const int* __restrict__ dst,
                       const int* __restrict__ off, int* __restrict__ cur,
                       const float* __restrict__ dis,
                       int2* __restrict__ eidx) {
    int e = blockIdx.x * 256 + threadIdx.x;
    if (e < NE) {
        int s = src[e], d = dst[e];
        int pos = off[d] + atomicAdd(&cur[d], 1);
        float w = dis[s] * dis[d];
        eidx[pos] = make_int2(s, __float_as_int(w));
    }
}

// ---------------- GEMM 1: H1 = X @ W1 (bf16 output) ----------------
__global__ __launch_bounds__(256) void k_gemm1(
    const float* __restrict__ X, const float* __restrict__ W,
    ushort_t* __restrict__ H)
{
    __shared__ float Ws[100 * 128];
    __shared__ float Xs[20 * 128];
    const int tid = threadIdx.x;
    const int tcol = tid & 15;
    const int trow = tid >> 4;
    const int row0 = blockIdx.x * 128;

    for (int idx = tid; idx < 100 * 128; idx += 256) {
        int k = idx >> 7, c = idx & 127;
        Ws[idx] = (c < 100) ? W[k * 100 + c] : 0.0f;
    }

    float acc[8][8];
    #pragma unroll
    for (int r = 0; r < 8; ++r)
        #pragma unroll
        for (int c = 0; c < 8; ++c) acc[r][c] = 0.0f;

    for (int kb = 0; kb < 5; ++kb) {
        __syncthreads();
        {
            int rl = tid >> 1, half = tid & 1;
            int grow = row0 + rl;
            const float* ap = X + (size_t)grow * 100 + kb * 20 + half * 10;
            bool v = grow < NN;
            float tmp[10];
            #pragma unroll
            for (int q = 0; q < 10; ++q) tmp[q] = v ? ap[q] : 0.0f;
            #pragma unroll
            for (int q = 0; q < 10; ++q) Xs[(half * 10 + q) * 128 + rl] = tmp[q];
        }
        __syncthreads();
        #pragma unroll 4
        for (int kk = 0; kk < 20; ++kk) {
            int k = kb * 20 + kk;
            float4 a0 = *(const float4*)&Xs[kk * 128 + trow * 8];
            float4 a1 = *(const float4*)&Xs[kk * 128 + trow * 8 + 4];
            float4 w0 = *(const float4*)&Ws[k * 128 + tcol * 8];
            float4 w1 = *(const float4*)&Ws[k * 128 + tcol * 8 + 4];
            float av[8] = {a0.x, a0.y, a0.z, a0.w, a1.x, a1.y, a1.z, a1.w};
            float wv[8] = {w0.x, w0.y, w0.z, w0.w, w1.x, w1.y, w1.z, w1.w};
            #pragma unroll
            for (int r = 0; r < 8; ++r)
                #pragma unroll
                for (int c = 0; c < 8; ++c)
                    acc[r][c] += av[r] * wv[c];
        }
    }

    #pragma unroll
    for (int r = 0; r < 8; ++r) {
        int gr = row0 + trow * 8 + r;
        if (gr >= NN) continue;
        #pragma unroll
        for (int cc = 0; cc < 8; cc += 4) {
            int c = tcol * 8 + cc;
            if (c < 100) {
                ushort4 o;
                o.x = f2bf(acc[r][cc]);
                o.y = f2bf(acc[r][cc + 1]);
                o.z = f2bf(acc[r][cc + 2]);
                o.w = f2bf(acc[r][cc + 3]);
                *(ushort4*)&H[(size_t)gr * 100 + c] = o;
            }
        }
    }
}

// ---------------- aggregation (gather, bf16 in) ----------------
// PHASE 1: outb = bf16(relu(self + edgesum + b1))   PHASE 2: outf = self + edgesum (fp32)
template<int PHASE>
__global__ __launch_bounds__(256) void k_agg(
    const ushort_t* __restrict__ Hin,
    const int* __restrict__ off, const int2* __restrict__ eidx,
    const float* __restrict__ dis, const float* __restrict__ bias,
    ushort_t* __restrict__ outb, float* __restrict__ outf)
{
    int i = blockIdx.x * 256 + threadIdx.x;
    if (i >= NN * 25) return;
    int node = i / 25;
    int c4 = i - node * 25;
    int col = c4 * 4;

    float d = dis[node];
    float d2 = d * d;
    ushort4 sv = *(const ushort4*)(Hin + (size_t)node * 100 + col);
    float a0 = bf2f(sv.x) * d2;
    float a1 = bf2f(sv.y) * d2;
    float a2 = bf2f(sv.z) * d2;
    float a3 = bf2f(sv.w) * d2;

    int e0 = off[node], e1 = off[node + 1];
    int e = e0;
    for (; e + 1 < e1; e += 2) {
        int2 p0 = eidx[e];
        int2 p1 = eidx[e + 1];
        ushort4 h0 = *(const ushort4*)(Hin + (size_t)p0.x * 100 + col);
        ushort4 h1 = *(const ushort4*)(Hin + (size_t)p1.x * 100 + col);
        float w0 = __int_as_float(p0.y);
        float w1 = __int_as_float(p1.y);
        a0 += bf2f(h0.x) * w0; a1 += bf2f(h0.y) * w0;
        a2 += bf2f(h0.z) * w0; a3 += bf2f(h0.w) * w0;
        a0 += bf2f(h1.x) * w1; a1 += bf2f(h1.y) * w1;
        a2 += bf2f(h1.z) * w1; a3 += bf2f(h1.w) * w1;
    }
    if (e < e1) {
        int2 p0 = eidx[e];
        ushort4 h0 = *(const ushort4*)(Hin + (size_t)p0.x * 100 + col);
        float w0 = __int_as_float(p0.y);
        a0 += bf2f(h0.x) * w0; a1 += bf2f(h0.y) * w0;
        a2 += bf2f(h0.z) * w0; a3 += bf2f(h0.w) * w0;
    }

    if (PHASE == 1) {
        float4 b = *(const float4*)(bias + col);
        a0 = fmaxf(a0 + b.x, 0.0f);
        a1 = fmaxf(a1 + b.y, 0.0f);
        a2 = fmaxf(a2 + b.z, 0.0f);
        a3 = fmaxf(a3 + b.w, 0.0f);
        ushort4 o;
        o.x = f2bf(a0); o.y = f2bf(a1); o.z = f2bf(a2); o.w = f2bf(a3);
        *(ushort4*)(outb + (size_t)node * 100 + col) = o;
    } else {
        *(float4*)(outf + (size_t)i * 4) = make_float4(a0, a1, a2, a3);
    }
}

// ---------------- GEMM 2: out = AGG2 @ [Wmu|Wls] + [bmu|bls] ----------------
__global__ __launch_bounds__(256) void k_gemm2(
    const float* __restrict__ A,
    const float* __restrict__ Wmu, const float* __restrict__ Wls,
    const float* __restrict__ bmu, const float* __restrict__ bls,
    float* __restrict__ outmu, float* __restrict__ outls)
{
    __shared__ float Ws[100 * 128];
    __shared__ float Xs[20 * 128];
    const int tid = threadIdx.x;
    const int tcol = tid & 15;
    const int trow = tid >> 4;
    const int row0 = blockIdx.x * 128;

    for (int idx = tid; idx < 100 * 128; idx += 256) {
        int k = idx >> 7, c = idx & 127;
        float w = 0.0f;
        if (c < 50) w = Wmu[k * 50 + c];
        else if (c < 100) w = Wls[k * 50 + (c - 50)];
        Ws[idx] = w;
    }

    float acc[8][8];
    #pragma unroll
    for (int r = 0; r < 8; ++r)
        #pragma unroll
        for (int c = 0; c < 8; ++c) acc[r][c] = 0.0f;

    for (int kb = 0; kb < 5; ++kb) {
        __syncthreads();
        {
            int rl = tid >> 1, half = tid & 1;
            int grow = row0 + rl;
            const float* ap = A + (size_t)grow * 100 + kb * 20 + half * 10;
            bool v = grow < NN;
            float tmp[10];
            #pragma unroll
            for (int q = 0; q < 10; ++q) tmp[q] = v ? ap[q] : 0.0f;
            #pragma unroll
            for (int q = 0; q < 10; ++q) Xs[(half * 10 + q) * 128 + rl] = tmp[q];
        }
        __syncthreads();
        #pragma unroll 4
        for (int kk = 0; kk < 20; ++kk) {
            int k = kb * 20 + kk;
            float4 a0 = *(const float4*)&Xs[kk * 128 + trow * 8];
            float4 a1 = *(const float4*)&Xs[kk * 128 + trow * 8 + 4];
            float4 w0 = *(const float4*)&Ws[k * 128 + tcol * 8];
            float4 w1 = *(const float4*)&Ws[k * 128 + tcol * 8 + 4];
            float av[8] = {a0.x, a0.y, a0.z, a0.w, a1.x, a1.y, a1.z, a1.w};
            float wv[8] = {w0.x, w0.y, w0.z, w0.w, w1.x, w1.y, w1.z, w1.w};
            #pragma unroll
            for (int r = 0; r < 8; ++r)
                #pragma unroll
                for (int c = 0; c < 8; ++c)
                    acc[r][c] += av[r] * wv[c];
        }
    }

    #pragma unroll
    for (int r = 0; r < 8; ++r) {
        int gr = row0 + trow * 8 + r;
        if (gr >= NN) continue;
        #pragma unroll
        for (int cc = 0; cc < 8; ++cc) {
            int c = tcol * 8 + cc;
            if (c < 50) {
                outmu[(size_t)gr * 50 + c] = acc[r][cc] + bmu[c];
            } else if (c < 100) {
                outls[(size_t)gr * 50 + (c - 50)] = acc[r][cc] + bls[c - 50];
            }
        }
    }
}

extern "C" void kernel_launch(void* const* d_in, const int* in_sizes, int n_in,
                              void* d_out, int out_size, void* d_ws, size_t ws_size,
                              hipStream_t stream)
{
    const float* x   = (const float*)d_in[0];
    const int*   ei  = (const int*)d_in[1];
    const float* W1  = (const float*)d_in[2];
    const float* b1  = (const float*)d_in[3];
    const float* Wmu = (const float*)d_in[4];
    const float* bmu = (const float*)d_in[5];
    const float* Wls = (const float*)d_in[6];
    const float* bls = (const float*)d_in[7];
    float* out = (float*)d_out;

    const int* src = ei;
    const int* dst = ei + NE;

    // workspace layout (4B element offsets)
    int*   wsI  = (int*)d_ws;
    float* wsF  = (float*)d_ws;
    int*      deg  = wsI;                        // 100000 (reused as cursor)
    int*      off  = wsI + 100000;               // 100001
    int*      bsum = wsI + 200064;               // 256
    int*      base = wsI + 200384;               // 256
    float*    dis  = wsF + 200704;               // 100000
    int2*     eidx = (int2*)(wsI + 300704);      // 800000 int2 (1.6M ints) -> ends 1900704
    ushort_t* H1b  = (ushort_t*)(wsI + 1900704); // 10M bf16 (5M ints) -> ends 6900704
    ushort_t* hb   = (ushort_t*)(wsI + 6900704); // 10M bf16 (5M ints) -> ends 11900704
    float*    AGG2 = wsF + 11900704;             // 10M fp32 -> ends 21900704

    hipMemsetAsync(deg, 0, NN * sizeof(int), stream);
    k_degi<<<(NE + 255) / 256, 256, 0, stream>>>(dst, deg);
    k_dis<<<(NN + 255) / 256, 256, 0, stream>>>(deg, dis);
    k_scan1<<<NBLK, 256, 0, stream>>>(deg, bsum);
    k_scan2<<<1, 256, 0, stream>>>(bsum, base);
    k_scan3<<<NBLK, 256, 0, stream>>>(deg, base, off);
    hipMemsetAsync(deg, 0, NN * sizeof(int), stream);   // reuse as cursor
    k_fill<<<(NE + 255) / 256, 256, 0, stream>>>(src, dst, off, deg, dis, eidx);

    // layer 1: H1 = bf16(X@W1) ; h = bf16(relu(Agg(H1) + b1))
    k_gemm1<<<(NN + 127) / 128, 256, 0, stream>>>(x, W1, H1b);
    k_agg<1><<<(NN * 25 + 255) / 256, 256, 0, stream>>>(H1b, off, eidx, dis, b1, hb, nullptr);
    // layer 2: AGG2 = Agg(h) ; out = AGG2@[Wmu|Wls] + bias
    k_agg<2><<<(NN * 25 + 255) / 256, 256, 0, stream>>>(hb, off, eidx, dis, b1, nullptr, AGG2);
    k_gemm2<<<(NN + 127) / 128, 256, 0, stream>>>(AGG2, Wmu, Wls, bmu, bls,
                                                  out, out + (size_t)NN * 50);
}

// Round 4
// 387.797 us; speedup vs baseline: 7.1535x; 1.1329x over previous
//
#include <hip/hip_runtime.h>

#define NN 100000
#define NE 800000
#define NBLK 196   // ceil(100000/512) scan blocks

typedef unsigned short ushort_t;
typedef unsigned int uint_t;

__device__ __forceinline__ float bf2f(ushort_t u) {
    union { unsigned int i; float f; } v; v.i = ((unsigned int)u) << 16; return v.f;
}
__device__ __forceinline__ ushort_t f2bf(float f) {
    union { float f; unsigned int i; } v; v.f = f;
    unsigned int b = v.i + 0x7FFF + ((v.i >> 16) & 1);
    return (ushort_t)(b >> 16);
}
__device__ __forceinline__ float lo_f(uint_t p) {
    union { unsigned int i; float f; } v; v.i = p << 16; return v.f;
}
__device__ __forceinline__ float hi_f(uint_t p) {
    union { unsigned int i; float f; } v; v.i = p & 0xffff0000u; return v.f;
}

// ---------------- degree (int) ----------------
__global__ void k_degi(const int* __restrict__ dst, int* __restrict__ deg) {
    int e = blockIdx.x * 256 + threadIdx.x;
    if (e < NE) atomicAdd(&deg[dst[e]], 1);
}

__global__ void k_dis(const int* __restrict__ deg, float* __restrict__ dis) {
    int i = blockIdx.x * 256 + threadIdx.x;
    if (i < NN) dis[i] = rsqrtf((float)deg[i] + 1.0f);
}

// ---------------- 3-pass exclusive scan of deg -> off ----------------
__global__ __launch_bounds__(256) void k_scan1(const int* __restrict__ deg, int* __restrict__ bsum) {
    __shared__ int s[256];
    int b = blockIdx.x, t = threadIdx.x;
    int g0 = b * 512;
    int v = 0;
    int g1 = g0 + t, g2 = g0 + t + 256;
    if (g1 < NN) v += deg[g1];
    if (g2 < NN) v += deg[g2];
    s[t] = v;
    __syncthreads();
    for (int o = 128; o > 0; o >>= 1) {
        if (t < o) s[t] += s[t + o];
        __syncthreads();
    }
    if (t == 0) bsum[b] = s[0];
}

__global__ __launch_bounds__(256) void k_scan2(const int* __restrict__ bsum, int* __restrict__ base) {
    __shared__ int s[NBLK];
    int t = threadIdx.x;
    if (t < NBLK) s[t] = bsum[t];
    __syncthreads();
    if (t == 0) {
        int run = 0;
        for (int i = 0; i < NBLK; ++i) { int v = s[i]; s[i] = run; run += v; }
    }
    __syncthreads();
    if (t < NBLK) base[t] = s[t];
}

__global__ __launch_bounds__(256) void k_scan3(const int* __restrict__ deg, const int* __restrict__ base,
                                               int* __restrict__ off) {
    __shared__ int s[2][512];
    int b = blockIdx.x, t = threadIdx.x;
    int g0 = b * 512;
    #pragma unroll
    for (int q = 0; q < 2; ++q) {
        int j = t + q * 256, g = g0 + j;
        s[0][j] = (g < NN) ? deg[g] : 0;
    }
    __syncthreads();
    int cur = 0;
    for (int o = 1; o < 512; o <<= 1) {
        int nxt = cur ^ 1;
        #pragma unroll
        for (int q = 0; q < 2; ++q) {
            int j = t + q * 256;
            s[nxt][j] = s[cur][j] + ((j >= o) ? s[cur][j - o] : 0);
        }
        cur = nxt;
        __syncthreads();
    }
    int bb = base[b];
    #pragma unroll
    for (int q = 0; q < 2; ++q) {
        int j = t + q * 256, g = g0 + j;
        if (g <= NN) off[g] = bb + ((j > 0) ? s[cur][j - 1] : 0);
    }
}

// ---------------- fill CSR slots: eidx[pos] = {src, bitcast(norm)} ----------------
__global__ void k_fill(const int* __restrict__ src, const int* __restrict__ dst,
                       const int* __restrict__ off, int* __restrict__ cur,
                       const float* __restrict__ dis,
                       int2* __restrict__ eidx) {
    int e = blockIdx.x * 256 + threadIdx.x;
    if (e < NE) {
        int s = src[e], d = dst[e];
        int pos = off[d] + atomicAdd(&cur[d], 1);
        float w = dis[s] * dis[d];
        eidx[pos] = make_int2(s, __float_as_int(w));
    }
}

// ---------------- GEMM 1: H1 = bf16(X @ W1), W in packed-bf16 LDS ----------------
__global__ __launch_bounds__(256, 4) void k_gemm1(
    const float* __restrict__ X, const float* __restrict__ W,
    ushort_t* __restrict__ H)
{
    __shared__ uint_t Ws[100 * 64];   // 25.6 KB: bf16 pairs, 128 padded cols
    __shared__ float  Xs[20 * 128];   // 10.2 KB
    const int tid = threadIdx.x;
    const int tcol = tid & 15;
    const int trow = tid >> 4;
    const int row0 = blockIdx.x * 128;

    for (int idx = tid; idx < 100 * 64; idx += 256) {
        int k = idx >> 6, c2 = idx & 63;
        int c0 = c2 * 2, c1 = c0 + 1;
        float w0 = (c0 < 100) ? W[k * 100 + c0] : 0.0f;
        float w1 = (c1 < 100) ? W[k * 100 + c1] : 0.0f;
        Ws[idx] = (uint_t)f2bf(w0) | ((uint_t)f2bf(w1) << 16);
    }

    float acc[8][8];
    #pragma unroll
    for (int r = 0; r < 8; ++r)
        #pragma unroll
        for (int c = 0; c < 8; ++c) acc[r][c] = 0.0f;

    for (int kb = 0; kb < 5; ++kb) {
        __syncthreads();
        {
            int rl = tid >> 1, half = tid & 1;
            int grow = row0 + rl;
            const float* ap = X + (size_t)grow * 100 + kb * 20 + half * 10;
            bool v = grow < NN;
            float tmp[10];
            #pragma unroll
            for (int q = 0; q < 10; ++q) tmp[q] = v ? ap[q] : 0.0f;
            #pragma unroll
            for (int q = 0; q < 10; ++q) Xs[(half * 10 + q) * 128 + rl] = tmp[q];
        }
        __syncthreads();
        #pragma unroll 4
        for (int kk = 0; kk < 20; ++kk) {
            int k = kb * 20 + kk;
            float4 a0 = *(const float4*)&Xs[kk * 128 + trow * 8];
            float4 a1 = *(const float4*)&Xs[kk * 128 + trow * 8 + 4];
            uint4 wp = *(const uint4*)&Ws[k * 64 + tcol * 4];
            float av[8] = {a0.x, a0.y, a0.z, a0.w, a1.x, a1.y, a1.z, a1.w};
            float wv[8] = {lo_f(wp.x), hi_f(wp.x), lo_f(wp.y), hi_f(wp.y),
                           lo_f(wp.z), hi_f(wp.z), lo_f(wp.w), hi_f(wp.w)};
            #pragma unroll
            for (int r = 0; r < 8; ++r)
                #pragma unroll
                for (int c = 0; c < 8; ++c)
                    acc[r][c] += av[r] * wv[c];
        }
    }

    #pragma unroll
    for (int r = 0; r < 8; ++r) {
        int gr = row0 + trow * 8 + r;
        if (gr >= NN) continue;
        #pragma unroll
        for (int cc = 0; cc < 8; cc += 4) {
            int c = tcol * 8 + cc;
            if (c < 100) {
                ushort4 o;
                o.x = f2bf(acc[r][cc]);
                o.y = f2bf(acc[r][cc + 1]);
                o.z = f2bf(acc[r][cc + 2]);
                o.w = f2bf(acc[r][cc + 3]);
                *(ushort4*)&H[(size_t)gr * 100 + c] = o;
            }
        }
    }
}

// ---------------- aggregation (gather, bf16 in) ----------------
// PHASE 1: outb = bf16(relu(self + edgesum + b1))   PHASE 2: outf = self + edgesum (fp32)
template<int PHASE>
__global__ __launch_bounds__(256) void k_agg(
    const ushort_t* __restrict__ Hin,
    const int* __restrict__ off, const int2* __restrict__ eidx,
    const float* __restrict__ dis, const float* __restrict__ bias,
    ushort_t* __restrict__ outb, float* __restrict__ outf)
{
    int i = blockIdx.x * 256 + threadIdx.x;
    if (i >= NN * 25) return;
    int node = i / 25;
    int c4 = i - node * 25;
    int col = c4 * 4;

    float d = dis[node];
    float d2 = d * d;
    ushort4 sv = *(const ushort4*)(Hin + (size_t)node * 100 + col);
    float a0 = bf2f(sv.x) * d2;
    float a1 = bf2f(sv.y) * d2;
    float a2 = bf2f(sv.z) * d2;
    float a3 = bf2f(sv.w) * d2;

    int e0 = off[node], e1 = off[node + 1];
    int e = e0;
    for (; e + 3 < e1; e += 4) {
        int2 p0 = eidx[e];
        int2 p1 = eidx[e + 1];
        int2 p2 = eidx[e + 2];
        int2 p3 = eidx[e + 3];
        ushort4 h0 = *(const ushort4*)(Hin + (size_t)p0.x * 100 + col);
        ushort4 h1 = *(const ushort4*)(Hin + (size_t)p1.x * 100 + col);
        ushort4 h2 = *(const ushort4*)(Hin + (size_t)p2.x * 100 + col);
        ushort4 h3 = *(const ushort4*)(Hin + (size_t)p3.x * 100 + col);
        float w0 = __int_as_float(p0.y);
        float w1 = __int_as_float(p1.y);
        float w2 = __int_as_float(p2.y);
        float w3 = __int_as_float(p3.y);
        a0 += bf2f(h0.x) * w0; a1 += bf2f(h0.y) * w0;
        a2 += bf2f(h0.z) * w0; a3 += bf2f(h0.w) * w0;
        a0 += bf2f(h1.x) * w1; a1 += bf2f(h1.y) * w1;
        a2 += bf2f(h1.z) * w1; a3 += bf2f(h1.w) * w1;
        a0 += bf2f(h2.x) * w2; a1 += bf2f(h2.y) * w2;
        a2 += bf2f(h2.z) * w2; a3 += bf2f(h2.w) * w2;
        a0 += bf2f(h3.x) * w3; a1 += bf2f(h3.y) * w3;
        a2 += bf2f(h3.z) * w3; a3 += bf2f(h3.w) * w3;
    }
    for (; e < e1; ++e) {
        int2 p0 = eidx[e];
        ushort4 h0 = *(const ushort4*)(Hin + (size_t)p0.x * 100 + col);
        float w0 = __int_as_float(p0.y);
        a0 += bf2f(h0.x) * w0; a1 += bf2f(h0.y) * w0;
        a2 += bf2f(h0.z) * w0; a3 += bf2f(h0.w) * w0;
    }

    if (PHASE == 1) {
        float4 b = *(const float4*)(bias + col);
        a0 = fmaxf(a0 + b.x, 0.0f);
        a1 = fmaxf(a1 + b.y, 0.0f);
        a2 = fmaxf(a2 + b.z, 0.0f);
        a3 = fmaxf(a3 + b.w, 0.0f);
        ushort4 o;
        o.x = f2bf(a0); o.y = f2bf(a1); o.z = f2bf(a2); o.w = f2bf(a3);
        *(ushort4*)(outb + (size_t)node * 100 + col) = o;
    } else {
        *(float4*)(outf + (size_t)i * 4) = make_float4(a0, a1, a2, a3);
    }
}

// ---------------- GEMM 2: out = AGG2 @ [Wmu|Wls] + [bmu|bls] ----------------
__global__ __launch_bounds__(256, 4) void k_gemm2(
    const float* __restrict__ A,
    const float* __restrict__ Wmu, const float* __restrict__ Wls,
    const float* __restrict__ bmu, const float* __restrict__ bls,
    float* __restrict__ outmu, float* __restrict__ outls)
{
    __shared__ uint_t Ws[100 * 64];
    __shared__ float  Xs[20 * 128];
    const int tid = threadIdx.x;
    const int tcol = tid & 15;
    const int trow = tid >> 4;
    const int row0 = blockIdx.x * 128;

    for (int idx = tid; idx < 100 * 64; idx += 256) {
        int k = idx >> 6, c2 = idx & 63;
        int c0 = c2 * 2, c1 = c0 + 1;
        float w0 = 0.0f, w1 = 0.0f;
        if (c0 < 50) w0 = Wmu[k * 50 + c0];
        else if (c0 < 100) w0 = Wls[k * 50 + (c0 - 50)];
        if (c1 < 50) w1 = Wmu[k * 50 + c1];
        else if (c1 < 100) w1 = Wls[k * 50 + (c1 - 50)];
        Ws[idx] = (uint_t)f2bf(w0) | ((uint_t)f2bf(w1) << 16);
    }

    float acc[8][8];
    #pragma unroll
    for (int r = 0; r < 8; ++r)
        #pragma unroll
        for (int c = 0; c < 8; ++c) acc[r][c] = 0.0f;

    for (int kb = 0; kb < 5; ++kb) {
        __syncthreads();
        {
            int rl = tid >> 1, half = tid & 1;
            int grow = row0 + rl;
            const float* ap = A + (size_t)grow * 100 + kb * 20 + half * 10;
            bool v = grow < NN;
            float tmp[10];
            #pragma unroll
            for (int q = 0; q < 10; ++q) tmp[q] = v ? ap[q] : 0.0f;
            #pragma unroll
            for (int q = 0; q < 10; ++q) Xs[(half * 10 + q) * 128 + rl] = tmp[q];
        }
        __syncthreads();
        #pragma unroll 4
        for (int kk = 0; kk < 20; ++kk) {
            int k = kb * 20 + kk;
            float4 a0 = *(const float4*)&Xs[kk * 128 + trow * 8];
            float4 a1 = *(const float4*)&Xs[kk * 128 + trow * 8 + 4];
            uint4 wp = *(const uint4*)&Ws[k * 64 + tcol * 4];
            float av[8] = {a0.x, a0.y, a0.z, a0.w, a1.x, a1.y, a1.z, a1.w};
            float wv[8] = {lo_f(wp.x), hi_f(wp.x), lo_f(wp.y), hi_f(wp.y),
                           lo_f(wp.z), hi_f(wp.z), lo_f(wp.w), hi_f(wp.w)};
            #pragma unroll
            for (int r = 0; r < 8; ++r)
                #pragma unroll
                for (int c = 0; c < 8; ++c)
                    acc[r][c] += av[r] * wv[c];
        }
    }

    #pragma unroll
    for (int r = 0; r < 8; ++r) {
        int gr = row0 + trow * 8 + r;
        if (gr >= NN) continue;
        #pragma unroll
        for (int cc = 0; cc < 8; ++cc) {
            int c = tcol * 8 + cc;
            if (c < 50) {
                outmu[(size_t)gr * 50 + c] = acc[r][cc] + bmu[c];
            } else if (c < 100) {
                outls[(size_t)gr * 50 + (c - 50)] = acc[r][cc] + bls[c - 50];
            }
        }
    }
}

extern "C" void kernel_launch(void* const* d_in, const int* in_sizes, int n_in,
                              void* d_out, int out_size, void* d_ws, size_t ws_size,
                              hipStream_t stream)
{
    const float* x   = (const float*)d_in[0];
    const int*   ei  = (const int*)d_in[1];
    const float* W1  = (const float*)d_in[2];
    const float* b1  = (const float*)d_in[3];
    const float* Wmu = (const float*)d_in[4];
    const float* bmu = (const float*)d_in[5];
    const float* Wls = (const float*)d_in[6];
    const float* bls = (const float*)d_in[7];
    float* out = (float*)d_out;

    const int* src = ei;
    const int* dst = ei + NE;

    // workspace layout (4B element offsets)
    int*   wsI  = (int*)d_ws;
    float* wsF  = (float*)d_ws;
    int*      deg  = wsI;                        // 100000 (reused as cursor)
    int*      off  = wsI + 100000;               // 100001
    int*      bsum = wsI + 200064;               // 256
    int*      base = wsI + 200384;               // 256
    float*    dis  = wsF + 200704;               // 100000
    int2*     eidx = (int2*)(wsI + 300704);      // 800000 int2 -> ends 1900704
    ushort_t* H1b  = (ushort_t*)(wsI + 1900704); // 10M bf16 -> ends 6900704
    ushort_t* hb   = (ushort_t*)(wsI + 6900704); // 10M bf16 -> ends 11900704
    float*    AGG2 = wsF + 11900704;             // 10M fp32 -> ends 21900704

    hipMemsetAsync(deg, 0, NN * sizeof(int), stream);
    k_degi<<<(NE + 255) / 256, 256, 0, stream>>>(dst, deg);
    k_dis<<<(NN + 255) / 256, 256, 0, stream>>>(deg, dis);
    k_scan1<<<NBLK, 256, 0, stream>>>(deg, bsum);
    k_scan2<<<1, 256, 0, stream>>>(bsum, base);
    k_scan3<<<NBLK, 256, 0, stream>>>(deg, base, off);
    hipMemsetAsync(deg, 0, NN * sizeof(int), stream);   // reuse as cursor
    k_fill<<<(NE + 255) / 256, 256, 0, stream>>>(src, dst, off, deg, dis, eidx);

    // layer 1: H1 = bf16(X@W1) ; h = bf16(relu(Agg(H1) + b1))
    k_gemm1<<<(NN + 127) / 128, 256, 0, stream>>>(x, W1, H1b);
    k_agg<1><<<(NN * 25 + 255) / 256, 256, 0, stream>>>(H1b, off, eidx, dis, b1, hb, nullptr);
    // layer 2: AGG2 = Agg(h) ; out = AGG2@[Wmu|Wls] + bias
    k_agg<2><<<(NN * 25 + 255) / 256, 256, 0, stream>>>(hb, off, eidx, dis, b1, nullptr, AGG2);
    k_gemm2<<<(NN + 127) / 128, 256, 0, stream>>>(AGG2, Wmu, Wls, bmu, bls,
                                                  out, out + (size_t)NN * 50);
}

// Round 5
// 341.549 us; speedup vs baseline: 8.1222x; 1.1354x over previous
//
#include <hip/hip_runtime.h>

#define NN 100000
#define NE 800000
#define NBLK 196   // ceil(100000/512) scan blocks

typedef unsigned short ushort_t;
typedef unsigned int uint_t;
typedef __attribute__((ext_vector_type(8))) short short8;
typedef __attribute__((ext_vector_type(4))) float floatx4;

__device__ __forceinline__ float bf2f(ushort_t u) {
    union { unsigned int i; float f; } v; v.i = ((unsigned int)u) << 16; return v.f;
}
__device__ __forceinline__ ushort_t f2bf(float f) {
    union { float f; unsigned int i; } v; v.f = f;
    unsigned int b = v.i + 0x7FFF + ((v.i >> 16) & 1);
    return (ushort_t)(b >> 16);
}
__device__ __forceinline__ uint_t pack2(float a, float b) {
    return (uint_t)f2bf(a) | ((uint_t)f2bf(b) << 16);
}

// ---------------- degree (int) ----------------
__global__ void k_degi(const int* __restrict__ dst, int* __restrict__ deg) {
    int e = blockIdx.x * 256 + threadIdx.x;
    if (e < NE) atomicAdd(&deg[dst[e]], 1);
}

__global__ void k_dis(const int* __restrict__ deg, float* __restrict__ dis) {
    int i = blockIdx.x * 256 + threadIdx.x;
    if (i < NN) dis[i] = rsqrtf((float)deg[i] + 1.0f);
}

// ---------------- 3-pass exclusive scan of deg -> off ----------------
__global__ __launch_bounds__(256) void k_scan1(const int* __restrict__ deg, int* __restrict__ bsum) {
    __shared__ int s[256];
    int b = blockIdx.x, t = threadIdx.x;
    int g0 = b * 512;
    int v = 0;
    int g1 = g0 + t, g2 = g0 + t + 256;
    if (g1 < NN) v += deg[g1];
    if (g2 < NN) v += deg[g2];
    s[t] = v;
    __syncthreads();
    for (int o = 128; o > 0; o >>= 1) {
        if (t < o) s[t] += s[t + o];
        __syncthreads();
    }
    if (t == 0) bsum[b] = s[0];
}

__global__ __launch_bounds__(256) void k_scan2(const int* __restrict__ bsum, int* __restrict__ base) {
    __shared__ int s[NBLK];
    int t = threadIdx.x;
    if (t < NBLK) s[t] = bsum[t];
    __syncthreads();
    if (t == 0) {
        int run = 0;
        for (int i = 0; i < NBLK; ++i) { int v = s[i]; s[i] = run; run += v; }
    }
    __syncthreads();
    if (t < NBLK) base[t] = s[t];
}

__global__ __launch_bounds__(256) void k_scan3(const int* __restrict__ deg, const int* __restrict__ base,
                                               int* __restrict__ off) {
    __shared__ int s[2][512];
    int b = blockIdx.x, t = threadIdx.x;
    int g0 = b * 512;
    #pragma unroll
    for (int q = 0; q < 2; ++q) {
        int j = t + q * 256, g = g0 + j;
        s[0][j] = (g < NN) ? deg[g] : 0;
    }
    __syncthreads();
    int cur = 0;
    for (int o = 1; o < 512; o <<= 1) {
        int nxt = cur ^ 1;
        #pragma unroll
        for (int q = 0; q < 2; ++q) {
            int j = t + q * 256;
            s[nxt][j] = s[cur][j] + ((j >= o) ? s[cur][j - o] : 0);
        }
        cur = nxt;
        __syncthreads();
    }
    int bb = base[b];
    #pragma unroll
    for (int q = 0; q < 2; ++q) {
        int j = t + q * 256, g = g0 + j;
        if (g <= NN) off[g] = bb + ((j > 0) ? s[cur][j - 1] : 0);
    }
}

// ---------------- fill CSR slots: eidx[pos] = {src, bitcast(norm)} ----------------
__global__ void k_fill(const int* __restrict__ src, const int* __restrict__ dst,
                       const int* __restrict__ off, int* __restrict__ cur,
                       const float* __restrict__ dis,
                       int2* __restrict__ eidx) {
    int e = blockIdx.x * 256 + threadIdx.x;
    if (e < NE) {
        int s = src[e], d = dst[e];
        int pos = off[d] + atomicAdd(&cur[d], 1);
        float w = dis[s] * dis[d];
        eidx[pos] = make_int2(s, __float_as_int(w));
    }
}

// ---------------- MFMA GEMM 1: H1b = bf16(X @ W1), X staged fp32->bf16 via LDS ----------------
// 256 thr = 4 waves, 64 rows/block, 7 col tiles (n=0..111, valid <100), K padded to 128.
__global__ __launch_bounds__(256) void k_gemm1_mfma(
    const float* __restrict__ X, const float* __restrict__ W,
    ushort_t* __restrict__ H)
{
    __shared__ ushort_t Wt[112 * 136];  // W^T bf16, [n][k], stride 136
    __shared__ ushort_t Xs[64 * 136];   // A tile bf16, [r][k], stride 136
    const int tid = threadIdx.x;
    const int row0 = blockIdx.x * 64;

    // prepack W^T (bf16 pairs)
    for (int idx = tid; idx < 112 * 64; idx += 256) {
        int n = idx >> 6, kp = idx & 63;
        int k0 = kp * 2, k1 = k0 + 1;
        float w0 = 0.0f, w1 = 0.0f;
        if (n < 100) {
            if (k0 < 100) w0 = W[k0 * 100 + n];
            if (k1 < 100) w1 = W[k1 * 100 + n];
        }
        *(uint_t*)&Wt[n * 136 + k0] = pack2(w0, w1);
    }
    // stage X tile -> bf16
    for (int idx = tid; idx < 64 * 25; idx += 256) {
        int r = idx / 25, q = idx - r * 25;
        int gr = row0 + r;
        float4 v = make_float4(0.f, 0.f, 0.f, 0.f);
        if (gr < NN) v = *(const float4*)&X[(size_t)gr * 100 + q * 4];
        uint2 p;
        p.x = pack2(v.x, v.y);
        p.y = pack2(v.z, v.w);
        *(uint2*)&Xs[r * 136 + q * 4] = p;
    }
    // zero pad cols 100..135
    for (int idx = tid; idx < 64 * 9; idx += 256) {
        int r = idx / 9, g = idx - r * 9;
        *(uint2*)&Xs[r * 136 + 100 + g * 4] = make_uint2(0, 0);
    }
    __syncthreads();

    const int wave = tid >> 6, lane = tid & 63;
    const int quad = lane >> 4, l16 = lane & 15;

    floatx4 acc[7];
    #pragma unroll
    for (int t = 0; t < 7; ++t) acc[t] = (floatx4){0.f, 0.f, 0.f, 0.f};

    #pragma unroll
    for (int k0 = 0; k0 < 128; k0 += 32) {
        short8 af = *(const short8*)&Xs[(wave * 16 + l16) * 136 + k0 + quad * 8];
        #pragma unroll
        for (int t = 0; t < 7; ++t) {
            short8 bf = *(const short8*)&Wt[(t * 16 + l16) * 136 + k0 + quad * 8];
            acc[t] = __builtin_amdgcn_mfma_f32_16x16x32_bf16(af, bf, acc[t], 0, 0, 0);
        }
    }

    const int mbase = row0 + wave * 16 + quad * 4;
    #pragma unroll
    for (int reg = 0; reg < 4; ++reg) {
        int m = mbase + reg;
        if (m >= NN) continue;
        #pragma unroll
        for (int t = 0; t < 7; ++t) {
            int n = t * 16 + l16;
            if (n < 100) H[(size_t)m * 128 + n] = f2bf(acc[t][reg]);
        }
    }
}

// ---------------- MFMA GEMM 2: out = AGG2b @ [Wmu|Wls] + [bmu|bls] ----------------
__global__ __launch_bounds__(256) void k_gemm2_mfma(
    const ushort_t* __restrict__ A,   // bf16, stride 128, k-padded w/ zeros
    const float* __restrict__ Wmu, const float* __restrict__ Wls,
    const float* __restrict__ bmu, const float* __restrict__ bls,
    float* __restrict__ outmu, float* __restrict__ outls)
{
    __shared__ ushort_t Wt[112 * 136];
    const int tid = threadIdx.x;
    const int row0 = blockIdx.x * 64;

    for (int idx = tid; idx < 112 * 64; idx += 256) {
        int n = idx >> 6, kp = idx & 63;
        int k0 = kp * 2, k1 = k0 + 1;
        float w0 = 0.0f, w1 = 0.0f;
        if (n < 50) {
            if (k0 < 100) w0 = Wmu[k0 * 50 + n];
            if (k1 < 100) w1 = Wmu[k1 * 50 + n];
        } else if (n < 100) {
            if (k0 < 100) w0 = Wls[k0 * 50 + (n - 50)];
            if (k1 < 100) w1 = Wls[k1 * 50 + (n - 50)];
        }
        *(uint_t*)&Wt[n * 136 + k0] = pack2(w0, w1);
    }
    __syncthreads();

    const int wave = tid >> 6, lane = tid & 63;
    const int quad = lane >> 4, l16 = lane & 15;
    int arow = row0 + wave * 16 + l16;
    if (arow >= NN) arow = NN - 1;

    floatx4 acc[7];
    #pragma unroll
    for (int t = 0; t < 7; ++t) acc[t] = (floatx4){0.f, 0.f, 0.f, 0.f};

    #pragma unroll
    for (int k0 = 0; k0 < 128; k0 += 32) {
        short8 af = *(const short8*)&A[(size_t)arow * 128 + k0 + quad * 8];
        #pragma unroll
        for (int t = 0; t < 7; ++t) {
            short8 bf = *(const short8*)&Wt[(t * 16 + l16) * 136 + k0 + quad * 8];
            acc[t] = __builtin_amdgcn_mfma_f32_16x16x32_bf16(af, bf, acc[t], 0, 0, 0);
        }
    }

    const int mbase = row0 + wave * 16 + quad * 4;
    #pragma unroll
    for (int reg = 0; reg < 4; ++reg) {
        int m = mbase + reg;
        if (m >= NN) continue;
        #pragma unroll
        for (int t = 0; t < 7; ++t) {
            int n = t * 16 + l16;
            if (n < 50) {
                outmu[(size_t)m * 50 + n] = acc[t][reg] + bmu[n];
            } else if (n < 100) {
                outls[(size_t)m * 50 + (n - 50)] = acc[t][reg] + bls[n - 50];
            }
        }
    }
}

// ---------------- aggregation (gather, bf16 in/out, stride 128) ----------------
// PHASE 1: out = bf16(relu(self + edgesum + b1))   PHASE 2: out = bf16(self + edgesum), k-pad zeroed
template<int PHASE>
__global__ __launch_bounds__(256) void k_agg(
    const ushort_t* __restrict__ Hin,
    const int* __restrict__ off, const int2* __restrict__ eidx,
    const float* __restrict__ dis, const float* __restrict__ bias,
    ushort_t* __restrict__ outb)
{
    int i = blockIdx.x * 256 + threadIdx.x;
    if (i >= NN * 25) return;
    int node = i / 25;
    int c4 = i - node * 25;
    int col = c4 * 4;

    float d = dis[node];
    float d2 = d * d;
    ushort4 sv = *(const ushort4*)(Hin + (size_t)node * 128 + col);
    float a0 = bf2f(sv.x) * d2;
    float a1 = bf2f(sv.y) * d2;
    float a2 = bf2f(sv.z) * d2;
    float a3 = bf2f(sv.w) * d2;

    int e0 = off[node], e1 = off[node + 1];
    int e = e0;
    for (; e + 3 < e1; e += 4) {
        int2 p0 = eidx[e];
        int2 p1 = eidx[e + 1];
        int2 p2 = eidx[e + 2];
        int2 p3 = eidx[e + 3];
        ushort4 h0 = *(const ushort4*)(Hin + (size_t)p0.x * 128 + col);
        ushort4 h1 = *(const ushort4*)(Hin + (size_t)p1.x * 128 + col);
        ushort4 h2 = *(const ushort4*)(Hin + (size_t)p2.x * 128 + col);
        ushort4 h3 = *(const ushort4*)(Hin + (size_t)p3.x * 128 + col);
        float w0 = __int_as_float(p0.y);
        float w1 = __int_as_float(p1.y);
        float w2 = __int_as_float(p2.y);
        float w3 = __int_as_float(p3.y);
        a0 += bf2f(h0.x) * w0; a1 += bf2f(h0.y) * w0;
        a2 += bf2f(h0.z) * w0; a3 += bf2f(h0.w) * w0;
        a0 += bf2f(h1.x) * w1; a1 += bf2f(h1.y) * w1;
        a2 += bf2f(h1.z) * w1; a3 += bf2f(h1.w) * w1;
        a0 += bf2f(h2.x) * w2; a1 += bf2f(h2.y) * w2;
        a2 += bf2f(h2.z) * w2; a3 += bf2f(h2.w) * w2;
        a0 += bf2f(h3.x) * w3; a1 += bf2f(h3.y) * w3;
        a2 += bf2f(h3.z) * w3; a3 += bf2f(h3.w) * w3;
    }
    for (; e < e1; ++e) {
        int2 p0 = eidx[e];
        ushort4 h0 = *(const ushort4*)(Hin + (size_t)p0.x * 128 + col);
        float w0 = __int_as_float(p0.y);
        a0 += bf2f(h0.x) * w0; a1 += bf2f(h0.y) * w0;
        a2 += bf2f(h0.z) * w0; a3 += bf2f(h0.w) * w0;
    }

    if (PHASE == 1) {
        float4 b = *(const float4*)(bias + col);
        a0 = fmaxf(a0 + b.x, 0.0f);
        a1 = fmaxf(a1 + b.y, 0.0f);
        a2 = fmaxf(a2 + b.z, 0.0f);
        a3 = fmaxf(a3 + b.w, 0.0f);
    }
    ushort4 o;
    o.x = f2bf(a0); o.y = f2bf(a1); o.z = f2bf(a2); o.w = f2bf(a3);
    *(ushort4*)(outb + (size_t)node * 128 + col) = o;

    if (PHASE == 2 && c4 >= 18) {
        // zero k-pad cols 100..127 (7 ushort4 groups handled by c4=18..24)
        *(ushort4*)(outb + (size_t)node * 128 + 100 + (c4 - 18) * 4) =
            make_ushort4(0, 0, 0, 0);
    }
}

extern "C" void kernel_launch(void* const* d_in, const int* in_sizes, int n_in,
                              void* d_out, int out_size, void* d_ws, size_t ws_size,
                              hipStream_t stream)
{
    const float* x   = (const float*)d_in[0];
    const int*   ei  = (const int*)d_in[1];
    const float* W1  = (const float*)d_in[2];
    const float* b1  = (const float*)d_in[3];
    const float* Wmu = (const float*)d_in[4];
    const float* bmu = (const float*)d_in[5];
    const float* Wls = (const float*)d_in[6];
    const float* bls = (const float*)d_in[7];
    float* out = (float*)d_out;

    const int* src = ei;
    const int* dst = ei + NE;

    // workspace layout (4B element offsets)
    int*   wsI  = (int*)d_ws;
    float* wsF  = (float*)d_ws;
    int*      deg  = wsI;                         // 100000 (reused as cursor)
    int*      off  = wsI + 100000;                // 100001
    int*      bsum = wsI + 200064;                // 256
    int*      base = wsI + 200384;                // 256
    float*    dis  = wsF + 200704;                // 100000
    int2*     eidx = (int2*)(wsI + 300704);       // 800000 int2 -> ends 1900704
    ushort_t* H1b  = (ushort_t*)(wsI + 1900704);  // 100000*128 bf16 (6.4M ints) -> 8300704
    ushort_t* hb   = (ushort_t*)(wsI + 8300704);  // -> 14700704
    ushort_t* A2b  = (ushort_t*)(wsI + 14700704); // -> 21100704

    hipMemsetAsync(deg, 0, NN * sizeof(int), stream);
    k_degi<<<(NE + 255) / 256, 256, 0, stream>>>(dst, deg);
    k_dis<<<(NN + 255) / 256, 256, 0, stream>>>(deg, dis);
    k_scan1<<<NBLK, 256, 0, stream>>>(deg, bsum);
    k_scan2<<<1, 256, 0, stream>>>(bsum, base);
    k_scan3<<<NBLK, 256, 0, stream>>>(deg, base, off);
    hipMemsetAsync(deg, 0, NN * sizeof(int), stream);   // reuse as cursor
    k_fill<<<(NE + 255) / 256, 256, 0, stream>>>(src, dst, off, deg, dis, eidx);

    const int gblk = (NN + 63) / 64;
    // layer 1: H1b = bf16(X@W1) ; hb = bf16(relu(Agg(H1b) + b1))
    k_gemm1_mfma<<<gblk, 256, 0, stream>>>(x, W1, H1b);
    k_agg<1><<<(NN * 25 + 255) / 256, 256, 0, stream>>>(H1b, off, eidx, dis, b1, hb);
    // layer 2: A2b = bf16(Agg(hb)) ; out = A2b@[Wmu|Wls] + bias
    k_agg<2><<<(NN * 25 + 255) / 256, 256, 0, stream>>>(hb, off, eidx, dis, b1, A2b);
    k_gemm2_mfma<<<gblk, 256, 0, stream>>>(A2b, Wmu, Wls, bmu, bls,
                                           out, out + (size_t)NN * 50);
}

// Round 6
// 293.607 us; speedup vs baseline: 9.4484x; 1.1633x over previous
//
#include <hip/hip_runtime.h>

#define NN 100000
#define NE 800000
#define NBLK 196   // ceil(100000/512) scan blocks

typedef unsigned short ushort_t;
typedef unsigned int uint_t;
typedef __attribute__((ext_vector_type(8))) short short8;
typedef __attribute__((ext_vector_type(4))) float floatx4;

__device__ __forceinline__ float bf2f(ushort_t u) {
    union { unsigned int i; float f; } v; v.i = ((unsigned int)u) << 16; return v.f;
}
__device__ __forceinline__ ushort_t f2bf(float f) {
    union { float f; unsigned int i; } v; v.f = f;
    unsigned int b = v.i + 0x7FFF + ((v.i >> 16) & 1);
    return (ushort_t)(b >> 16);
}
__device__ __forceinline__ uint_t pack2(float a, float b) {
    return (uint_t)f2bf(a) | ((uint_t)f2bf(b) << 16);
}

// ---------------- degree (int) ----------------
__global__ void k_degi(const int* __restrict__ dst, int* __restrict__ deg) {
    int e = blockIdx.x * 256 + threadIdx.x;
    if (e < NE) atomicAdd(&deg[dst[e]], 1);
}

__global__ void k_dis(const int* __restrict__ deg, float* __restrict__ dis) {
    int i = blockIdx.x * 256 + threadIdx.x;
    if (i < NN) dis[i] = rsqrtf((float)deg[i] + 1.0f);
}

// ---------------- 3-pass exclusive scan of deg -> off ----------------
__global__ __launch_bounds__(256) void k_scan1(const int* __restrict__ deg, int* __restrict__ bsum) {
    __shared__ int s[256];
    int b = blockIdx.x, t = threadIdx.x;
    int g0 = b * 512;
    int v = 0;
    int g1 = g0 + t, g2 = g0 + t + 256;
    if (g1 < NN) v += deg[g1];
    if (g2 < NN) v += deg[g2];
    s[t] = v;
    __syncthreads();
    for (int o = 128; o > 0; o >>= 1) {
        if (t < o) s[t] += s[t + o];
        __syncthreads();
    }
    if (t == 0) bsum[b] = s[0];
}

__global__ __launch_bounds__(256) void k_scan2(const int* __restrict__ bsum, int* __restrict__ base) {
    __shared__ int s[NBLK];
    int t = threadIdx.x;
    if (t < NBLK) s[t] = bsum[t];
    __syncthreads();
    if (t == 0) {
        int run = 0;
        for (int i = 0; i < NBLK; ++i) { int v = s[i]; s[i] = run; run += v; }
    }
    __syncthreads();
    if (t < NBLK) base[t] = s[t];
}

__global__ __launch_bounds__(256) void k_scan3(const int* __restrict__ deg, const int* __restrict__ base,
                                               int* __restrict__ off) {
    __shared__ int s[2][512];
    int b = blockIdx.x, t = threadIdx.x;
    int g0 = b * 512;
    #pragma unroll
    for (int q = 0; q < 2; ++q) {
        int j = t + q * 256, g = g0 + j;
        s[0][j] = (g < NN) ? deg[g] : 0;
    }
    __syncthreads();
    int cur = 0;
    for (int o = 1; o < 512; o <<= 1) {
        int nxt = cur ^ 1;
        #pragma unroll
        for (int q = 0; q < 2; ++q) {
            int j = t + q * 256;
            s[nxt][j] = s[cur][j] + ((j >= o) ? s[cur][j - o] : 0);
        }
        cur = nxt;
        __syncthreads();
    }
    int bb = base[b];
    #pragma unroll
    for (int q = 0; q < 2; ++q) {
        int j = t + q * 256, g = g0 + j;
        if (g <= NN) off[g] = bb + ((j > 0) ? s[cur][j - 1] : 0);
    }
}

// ---------------- fill CSR slots: eidx[pos] = {src, bitcast(norm)} ----------------
__global__ void k_fill(const int* __restrict__ src, const int* __restrict__ dst,
                       const int* __restrict__ off, int* __restrict__ cur,
                       const float* __restrict__ dis,
                       int2* __restrict__ eidx) {
    int e = blockIdx.x * 256 + threadIdx.x;
    if (e < NE) {
        int s = src[e], d = dst[e];
        int pos = off[d] + atomicAdd(&cur[d], 1);
        float w = dis[s] * dis[d];
        eidx[pos] = make_int2(s, __float_as_int(w));
    }
}

// ---------------- one-shot W^T pre-pack to global (bf16 pairs) ----------------
// grid 224 x 64: block b -> mat = b/112, n = b%112; lane = k-pair
__global__ __launch_bounds__(64) void k_packW(
    const float* __restrict__ W1,
    const float* __restrict__ Wmu, const float* __restrict__ Wls,
    uint_t* __restrict__ Wt1g, uint_t* __restrict__ Wt2g)
{
    int b = blockIdx.x;
    int mat = b / 112, n = b - mat * 112;
    int kp = threadIdx.x;
    int k0 = kp * 2, k1 = k0 + 1;
    float w0 = 0.0f, w1 = 0.0f;
    if (mat == 0) {
        if (n < 100) {
            if (k0 < 100) w0 = W1[k0 * 100 + n];
            if (k1 < 100) w1 = W1[k1 * 100 + n];
        }
        Wt1g[n * 64 + kp] = pack2(w0, w1);
    } else {
        if (n < 50) {
            if (k0 < 100) w0 = Wmu[k0 * 50 + n];
            if (k1 < 100) w1 = Wmu[k1 * 50 + n];
        } else if (n < 100) {
            if (k0 < 100) w0 = Wls[k0 * 50 + (n - 50)];
            if (k1 < 100) w1 = Wls[k1 * 50 + (n - 50)];
        }
        Wt2g[n * 64 + kp] = pack2(w0, w1);
    }
}

// ---------------- MFMA GEMM 1: H1b = bf16(X @ W1) ----------------
// 4 waves, 64 rows/block; A-fragments loaded straight from X (fp32) and
// converted in registers; W^T copied coalesced from pre-packed global.
__global__ __launch_bounds__(256) void k_gemm1_mfma(
    const float* __restrict__ X, const uint_t* __restrict__ Wtg,
    ushort_t* __restrict__ H)
{
    __shared__ ushort_t Ws[112 * 136];   // 30.5 KB
    const int tid = threadIdx.x;
    const int row0 = blockIdx.x * 64;

    for (int idx = tid; idx < 112 * 16; idx += 256) {
        int n = idx >> 4, c = idx & 15;
        uint4 v = *(const uint4*)&Wtg[n * 64 + c * 4];
        *(uint4*)&Ws[n * 136 + c * 8] = v;
    }
    __syncthreads();

    const int wave = tid >> 6, lane = tid & 63;
    const int quad = lane >> 4, l16 = lane & 15;
    int row = row0 + wave * 16 + l16;
    if (row >= NN) row = NN - 1;
    const float* xp = X + (size_t)row * 100;

    floatx4 acc[7];
    #pragma unroll
    for (int t = 0; t < 7; ++t) acc[t] = (floatx4){0.f, 0.f, 0.f, 0.f};

    #pragma unroll
    for (int ks = 0; ks < 4; ++ks) {
        const int k0 = ks * 32;
        const int kb = k0 + quad * 8;
        short8 af;
        if (ks < 3) {
            float4 u = *(const float4*)&xp[kb];
            float4 v = *(const float4*)&xp[kb + 4];
            af[0] = (short)f2bf(u.x); af[1] = (short)f2bf(u.y);
            af[2] = (short)f2bf(u.z); af[3] = (short)f2bf(u.w);
            af[4] = (short)f2bf(v.x); af[5] = (short)f2bf(v.y);
            af[6] = (short)f2bf(v.z); af[7] = (short)f2bf(v.w);
        } else {
            af = (short8){0, 0, 0, 0, 0, 0, 0, 0};
            if (quad == 0) {
                float4 u = *(const float4*)&xp[96];
                af[0] = (short)f2bf(u.x); af[1] = (short)f2bf(u.y);
                af[2] = (short)f2bf(u.z); af[3] = (short)f2bf(u.w);
            }
        }
        #pragma unroll
        for (int t = 0; t < 7; ++t) {
            short8 bf = *(const short8*)&Ws[(t * 16 + l16) * 136 + kb];
            acc[t] = __builtin_amdgcn_mfma_f32_16x16x32_bf16(af, bf, acc[t], 0, 0, 0);
        }
    }

    const int mbase = row0 + wave * 16 + quad * 4;
    #pragma unroll
    for (int reg = 0; reg < 4; ++reg) {
        int m = mbase + reg;
        if (m >= NN) continue;
        #pragma unroll
        for (int t = 0; t < 7; ++t) {
            int n = t * 16 + l16;
            if (n < 100) H[(size_t)m * 128 + n] = f2bf(acc[t][reg]);
        }
    }
}

// ---------------- MFMA GEMM 2: out = AGG2b @ [Wmu|Wls] + [bmu|bls] ----------------
__global__ __launch_bounds__(256) void k_gemm2_mfma(
    const ushort_t* __restrict__ A,   // bf16, stride 128, k-padded w/ zeros
    const uint_t* __restrict__ Wtg,
    const float* __restrict__ bmu, const float* __restrict__ bls,
    float* __restrict__ outmu, float* __restrict__ outls)
{
    __shared__ ushort_t Ws[112 * 136];
    const int tid = threadIdx.x;
    const int row0 = blockIdx.x * 64;

    for (int idx = tid; idx < 112 * 16; idx += 256) {
        int n = idx >> 4, c = idx & 15;
        uint4 v = *(const uint4*)&Wtg[n * 64 + c * 4];
        *(uint4*)&Ws[n * 136 + c * 8] = v;
    }
    __syncthreads();

    const int wave = tid >> 6, lane = tid & 63;
    const int quad = lane >> 4, l16 = lane & 15;
    int arow = row0 + wave * 16 + l16;
    if (arow >= NN) arow = NN - 1;

    floatx4 acc[7];
    #pragma unroll
    for (int t = 0; t < 7; ++t) acc[t] = (floatx4){0.f, 0.f, 0.f, 0.f};

    #pragma unroll
    for (int k0 = 0; k0 < 128; k0 += 32) {
        short8 af = *(const short8*)&A[(size_t)arow * 128 + k0 + quad * 8];
        #pragma unroll
        for (int t = 0; t < 7; ++t) {
            short8 bf = *(const short8*)&Ws[(t * 16 + l16) * 136 + k0 + quad * 8];
            acc[t] = __builtin_amdgcn_mfma_f32_16x16x32_bf16(af, bf, acc[t], 0, 0, 0);
        }
    }

    const int mbase = row0 + wave * 16 + quad * 4;
    #pragma unroll
    for (int reg = 0; reg < 4; ++reg) {
        int m = mbase + reg;
        if (m >= NN) continue;
        #pragma unroll
        for (int t = 0; t < 7; ++t) {
            int n = t * 16 + l16;
            if (n < 50) {
                outmu[(size_t)m * 50 + n] = acc[t][reg] + bmu[n];
            } else if (n < 100) {
                outls[(size_t)m * 50 + (n - 50)] = acc[t][reg] + bls[n - 50];
            }
        }
    }
}

// ---------------- aggregation (gather, bf16 in/out, stride 128) ----------------
// PHASE 1: out = bf16(relu(self + edgesum + b1))   PHASE 2: out = bf16(self + edgesum), k-pad zeroed
template<int PHASE>
__global__ __launch_bounds__(256) void k_agg(
    const ushort_t* __restrict__ Hin,
    const int* __restrict__ off, const int2* __restrict__ eidx,
    const float* __restrict__ dis, const float* __restrict__ bias,
    ushort_t* __restrict__ outb)
{
    int i = blockIdx.x * 256 + threadIdx.x;
    if (i >= NN * 25) return;
    int node = i / 25;
    int c4 = i - node * 25;
    int col = c4 * 4;

    float d = dis[node];
    float d2 = d * d;
    ushort4 sv = *(const ushort4*)(Hin + (size_t)node * 128 + col);
    float a0 = bf2f(sv.x) * d2;
    float a1 = bf2f(sv.y) * d2;
    float a2 = bf2f(sv.z) * d2;
    float a3 = bf2f(sv.w) * d2;

    int e0 = off[node], e1 = off[node + 1];
    int e = e0;
    for (; e + 3 < e1; e += 4) {
        int2 p0 = eidx[e];
        int2 p1 = eidx[e + 1];
        int2 p2 = eidx[e + 2];
        int2 p3 = eidx[e + 3];
        ushort4 h0 = *(const ushort4*)(Hin + (size_t)p0.x * 128 + col);
        ushort4 h1 = *(const ushort4*)(Hin + (size_t)p1.x * 128 + col);
        ushort4 h2 = *(const ushort4*)(Hin + (size_t)p2.x * 128 + col);
        ushort4 h3 = *(const ushort4*)(Hin + (size_t)p3.x * 128 + col);
        float w0 = __int_as_float(p0.y);
        float w1 = __int_as_float(p1.y);
        float w2 = __int_as_float(p2.y);
        float w3 = __int_as_float(p3.y);
        a0 += bf2f(h0.x) * w0; a1 += bf2f(h0.y) * w0;
        a2 += bf2f(h0.z) * w0; a3 += bf2f(h0.w) * w0;
        a0 += bf2f(h1.x) * w1; a1 += bf2f(h1.y) * w1;
        a2 += bf2f(h1.z) * w1; a3 += bf2f(h1.w) * w1;
        a0 += bf2f(h2.x) * w2; a1 += bf2f(h2.y) * w2;
        a2 += bf2f(h2.z) * w2; a3 += bf2f(h2.w) * w2;
        a0 += bf2f(h3.x) * w3; a1 += bf2f(h3.y) * w3;
        a2 += bf2f(h3.z) * w3; a3 += bf2f(h3.w) * w3;
    }
    for (; e < e1; ++e) {
        int2 p0 = eidx[e];
        ushort4 h0 = *(const ushort4*)(Hin + (size_t)p0.x * 128 + col);
        float w0 = __int_as_float(p0.y);
        a0 += bf2f(h0.x) * w0; a1 += bf2f(h0.y) * w0;
        a2 += bf2f(h0.z) * w0; a3 += bf2f(h0.w) * w0;
    }

    if (PHASE == 1) {
        float4 b = *(const float4*)(bias + col);
        a0 = fmaxf(a0 + b.x, 0.0f);
        a1 = fmaxf(a1 + b.y, 0.0f);
        a2 = fmaxf(a2 + b.z, 0.0f);
        a3 = fmaxf(a3 + b.w, 0.0f);
    }
    ushort4 o;
    o.x = f2bf(a0); o.y = f2bf(a1); o.z = f2bf(a2); o.w = f2bf(a3);
    *(ushort4*)(outb + (size_t)node * 128 + col) = o;

    if (PHASE == 2 && c4 >= 18) {
        // zero k-pad cols 100..127 (7 ushort4 groups handled by c4=18..24)
        *(ushort4*)(outb + (size_t)node * 128 + 100 + (c4 - 18) * 4) =
            make_ushort4(0, 0, 0, 0);
    }
}

extern "C" void kernel_launch(void* const* d_in, const int* in_sizes, int n_in,
                              void* d_out, int out_size, void* d_ws, size_t ws_size,
                              hipStream_t stream)
{
    const float* x   = (const float*)d_in[0];
    const int*   ei  = (const int*)d_in[1];
    const float* W1  = (const float*)d_in[2];
    const float* b1  = (const float*)d_in[3];
    const float* Wmu = (const float*)d_in[4];
    const float* bmu = (const float*)d_in[5];
    const float* Wls = (const float*)d_in[6];
    const float* bls = (const float*)d_in[7];
    float* out = (float*)d_out;

    const int* src = ei;
    const int* dst = ei + NE;

    // workspace layout (4B element offsets)
    int*   wsI  = (int*)d_ws;
    float* wsF  = (float*)d_ws;
    int*      deg  = wsI;                         // 100000 (reused as cursor)
    int*      off  = wsI + 100000;                // 100001
    int*      bsum = wsI + 200064;                // 256
    int*      base = wsI + 200384;                // 256
    float*    dis  = wsF + 200704;                // 100000
    uint_t*   Wt1g = (uint_t*)(wsI + 300704);     // 7168 -> 307872
    uint_t*   Wt2g = (uint_t*)(wsI + 307872);     // 7168 -> 315040
    int2*     eidx = (int2*)(wsI + 315040);       // 800000 int2 -> ends 1915040
    ushort_t* H1b  = (ushort_t*)(wsI + 1915040);  // 100000*128 bf16 (6.4M ints) -> 8315040
    ushort_t* hb   = (ushort_t*)(wsI + 8315040);  // -> 14715040
    ushort_t* A2b  = (ushort_t*)(wsI + 14715040); // -> 21115040

    hipMemsetAsync(deg, 0, NN * sizeof(int), stream);
    k_degi<<<(NE + 255) / 256, 256, 0, stream>>>(dst, deg);
    k_dis<<<(NN + 255) / 256, 256, 0, stream>>>(deg, dis);
    k_scan1<<<NBLK, 256, 0, stream>>>(deg, bsum);
    k_scan2<<<1, 256, 0, stream>>>(bsum, base);
    k_scan3<<<NBLK, 256, 0, stream>>>(deg, base, off);
    hipMemsetAsync(deg, 0, NN * sizeof(int), stream);   // reuse as cursor
    k_fill<<<(NE + 255) / 256, 256, 0, stream>>>(src, dst, off, deg, dis, eidx);
    k_packW<<<224, 64, 0, stream>>>(W1, Wmu, Wls, Wt1g, Wt2g);

    const int gblk = (NN + 63) / 64;
    // layer 1: H1b = bf16(X@W1) ; hb = bf16(relu(Agg(H1b) + b1))
    k_gemm1_mfma<<<gblk, 256, 0, stream>>>(x, Wt1g, H1b);
    k_agg<1><<<(NN * 25 + 255) / 256, 256, 0, stream>>>(H1b, off, eidx, dis, b1, hb);
    // layer 2: A2b = bf16(Agg(hb)) ; out = A2b@[Wmu|Wls] + bias
    k_agg<2><<<(NN * 25 + 255) / 256, 256, 0, stream>>>(hb, off, eidx, dis, b1, A2b);
    k_gemm2_mfma<<<gblk, 256, 0, stream>>>(A2b, Wt2g, bmu, bls,
                                           out, out + (size_t)NN * 50);
}